// Round 8
// baseline (352.960 us; speedup 1.0000x reference)
//
#include <hip/hip_runtime.h>
#include <hip/hip_bf16.h>

#define N_NODES 50000
#define N_EDGES 600000
#define HID 128
#define N_LAYERS 3
#define N_GRAPHS 64
#define DEG_PAD 53248       // 52 blocks * 256 thr * 4 ints, zero-padded
#define SCAN_BLOCKS 52
#define LDK 136             // padded k-stride (bf16): 272B row ≡ 4 banks mod 32

typedef __attribute__((ext_vector_type(8))) short bf16x8;        // MFMA A/B frag
typedef __attribute__((ext_vector_type(8))) unsigned short u16x8; // 16B chunks
typedef __attribute__((ext_vector_type(4))) float f32x4;         // MFMA C/D frag

__device__ __forceinline__ unsigned short f2bf(float v) {
  __hip_bfloat16 b = __float2bfloat16(v);   // RNE
  unsigned short u;
  __builtin_memcpy(&u, &b, 2);
  return u;
}
__device__ __forceinline__ float bflo(unsigned int v) {
  unsigned int u = v << 16; float f; __builtin_memcpy(&f, &u, 4); return f;
}
__device__ __forceinline__ float bfhi(unsigned int v) {
  unsigned int u = v & 0xFFFF0000u; float f; __builtin_memcpy(&f, &u, 4); return f;
}

// ---------------- hb = bf16(x * node_imp), packed 2/uint ----------------
__global__ __launch_bounds__(256) void scale_kernel(const float* __restrict__ x,
                                                    const float* __restrict__ imp,
                                                    unsigned int* __restrict__ hb) {
  int i = blockIdx.x * 256 + threadIdx.x;            // over N_NODES*32 float4
  if (i >= N_NODES * (HID / 4)) return;
  float s = imp[i >> 5];
  float4 v = reinterpret_cast<const float4*>(x)[i];
  uint2 p;
  p.x = (unsigned)f2bf(v.x * s) | ((unsigned)f2bf(v.y * s) << 16);
  p.y = (unsigned)f2bf(v.z * s) | ((unsigned)f2bf(v.w * s) << 16);
  reinterpret_cast<uint2*>(hb)[i] = p;
}

// ---------------- W pre-convert: f32 [k][n] -> bf16 Wt [n][k] ----------------
__global__ __launch_bounds__(256) void wconv_kernel(const float* __restrict__ W1,
                                                    const float* __restrict__ W2,
                                                    unsigned short* __restrict__ wt) {
  const int m = blockIdx.x;                          // 0..5
  const float* src = (m < 3) ? (W1 + (size_t)m * HID * HID)
                             : (W2 + (size_t)(m - 3) * HID * HID);
  unsigned short* dst = wt + (size_t)m * HID * HID;
  const int tid = threadIdx.x;
  const int n = tid >> 1, kh = (tid & 1) * 64;
#pragma unroll 8
  for (int k = 0; k < 64; ++k)
    dst[n * HID + kh + k] = f2bf(src[(kh + k) * HID + n]);
}

// ---------------- CSR build: histogram ----------------
__global__ __launch_bounds__(256) void hist_kernel(const int* __restrict__ dst,
                                                   int* __restrict__ deg) {
  int e = blockIdx.x * 256 + threadIdx.x;
  if (e < N_EDGES) atomicAdd(&deg[dst[e]], 1);
}

// ------------- CSR scan, 3-kernel hierarchical (coalesced int4) -------------
__global__ __launch_bounds__(256) void scan1_kernel(const int* __restrict__ deg,
                                                    int* __restrict__ bsum) {
  int t = blockIdx.x * 256 + threadIdx.x;
  int4 d = reinterpret_cast<const int4*>(deg)[t];
  int s = d.x + d.y + d.z + d.w;
#pragma unroll
  for (int off = 1; off < 64; off <<= 1) s += __shfl_xor(s, off, 64);
  __shared__ int ws[4];
  if ((threadIdx.x & 63) == 0) ws[threadIdx.x >> 6] = s;
  __syncthreads();
  if (threadIdx.x == 0) bsum[blockIdx.x] = ws[0] + ws[1] + ws[2] + ws[3];
}

__global__ __launch_bounds__(64) void scan2_kernel(const int* __restrict__ bsum,
                                                   int* __restrict__ boff) {
  int t = threadIdx.x;                               // one wave
  int v = (t < SCAN_BLOCKS) ? bsum[t] : 0;
  int incl = v;
#pragma unroll
  for (int off = 1; off < 64; off <<= 1) {
    int u = __shfl_up(incl, off, 64);
    if (t >= off) incl += u;
  }
  if (t < SCAN_BLOCKS) boff[t] = incl - v;           // exclusive
}

__global__ __launch_bounds__(256) void scan3_kernel(const int* __restrict__ deg,
                                                    const int* __restrict__ boff,
                                                    int* __restrict__ rowptr,
                                                    int* __restrict__ cursor) {
  const int t = blockIdx.x * 256 + threadIdx.x;
  const int lane = threadIdx.x & 63, wid = threadIdx.x >> 6;
  int4 d = reinterpret_cast<const int4*>(deg)[t];
  int tsum = d.x + d.y + d.z + d.w;
  int incl = tsum;
#pragma unroll
  for (int off = 1; off < 64; off <<= 1) {
    int u = __shfl_up(incl, off, 64);
    if (lane >= off) incl += u;
  }
  __shared__ int wsum[4], wpre[4];
  if (lane == 63) wsum[wid] = incl;
  __syncthreads();
  if (threadIdx.x == 0) {
    int c = 0;
#pragma unroll
    for (int i = 0; i < 4; ++i) { wpre[i] = c; c += wsum[i]; }
  }
  __syncthreads();
  int run = boff[blockIdx.x] + wpre[wid] + (incl - tsum);
  int e1 = run + d.x, e2 = e1 + d.y, e3 = e2 + d.z, e4 = e3 + d.w;
  int base = t * 4;                                  // N_NODES % 4 == 0
  if (base < N_NODES) {
    reinterpret_cast<int4*>(cursor)[t] = make_int4(run, e1, e2, e3);
    rowptr[base + 1] = e1; rowptr[base + 2] = e2;
    rowptr[base + 3] = e3; rowptr[base + 4] = e4;
  }
  if (t == 0) rowptr[0] = 0;
}

// ---------------- CSR build: scatter edge sources by dst ----------------
__global__ __launch_bounds__(256) void scatter_kernel(const int* __restrict__ src,
                                                      const int* __restrict__ dst,
                                                      int* __restrict__ cursor,
                                                      int* __restrict__ esrc) {
  int e = blockIdx.x * 256 + threadIdx.x;
  if (e >= N_EDGES) return;
  int pos = atomicAdd(&cursor[dst[e]], 1);
  esrc[pos] = src[e];
}

// ---------------- fused layer: gather + MFMA MLP + h-update + pool ----------
// 512 thr = 8 waves; chunk = 128 rows; wave w owns rows [w*16, w*16+16).
// Phase A: stage Wt1 -> Wbuf. Phase B: per-node gather (z = h_self + sum h_src)
//          straight into Zbuf (wave-private rows, f32 accum, bf16 store).
// Then GEMM1 / relu / re-stage W2 / GEMM2 / epilogue as before.
// h ping-pong: reads hin, writes hout (skipped when store_h == 0, last layer).
__global__ __launch_bounds__(512, 4) void layer_kernel(
    const unsigned int* __restrict__ hin, const int* __restrict__ rowptr,
    const int* __restrict__ esrc, const unsigned short* __restrict__ wt1,
    const float* __restrict__ b1, const unsigned short* __restrict__ wt2,
    const float* __restrict__ b2, const float* __restrict__ imp,
    const int* __restrict__ batch, u16x8* __restrict__ hout,
    float* __restrict__ out, int lofs, int store_h) {
  __shared__ unsigned short Wbuf[128 * LDK];
  __shared__ unsigned short Zbuf[128 * LDK];
  __shared__ float pool_shf[HID];

  const int tid = threadIdx.x;
  const int lane = tid & 63;
  const int l15 = lane & 15, lg = lane >> 4;
  const int wrow0 = (tid >> 6) * 16;                 // wave's 16-row stripe
  const int row0 = blockIdx.x << 7;                  // chunk base

  {  // Phase A: stage Wt1 (16B chunks; 16 chunks per 128-elem row)
    const u16x8* wsrc = reinterpret_cast<const u16x8*>(wt1);
#pragma unroll
    for (int i = 0; i < 4; ++i) {
      int g = tid + i * 512;
      *reinterpret_cast<u16x8*>(&Wbuf[(g >> 4) * LDK + (g & 15) * 8]) = wsrc[g];
    }
  }

  // Phase B: gather this wave's 16 nodes (4-way edge MLP), write Zbuf bf16
  for (int n = 0; n < 16; ++n) {
    const int node = row0 + wrow0 + n;
    float ax = 0.f, ay = 0.f;
    if (node < N_NODES) {
      unsigned int self = hin[(size_t)node * 64 + lane];
      ax = bflo(self); ay = bfhi(self);              // self term (eps = 0)
      float bx = 0.f, by = 0.f, cx = 0.f, cy = 0.f, dx = 0.f, dy = 0.f;
      int s = rowptr[node], e = rowptr[node + 1];
      int j = s;
      for (; j + 4 <= e; j += 4) {                   // 4 outstanding loads
        unsigned int v0 = hin[(size_t)esrc[j] * 64 + lane];
        unsigned int v1 = hin[(size_t)esrc[j + 1] * 64 + lane];
        unsigned int v2 = hin[(size_t)esrc[j + 2] * 64 + lane];
        unsigned int v3 = hin[(size_t)esrc[j + 3] * 64 + lane];
        ax += bflo(v0); ay += bfhi(v0);
        bx += bflo(v1); by += bfhi(v1);
        cx += bflo(v2); cy += bfhi(v2);
        dx += bflo(v3); dy += bfhi(v3);
      }
      for (; j < e; ++j) {
        unsigned int v = hin[(size_t)esrc[j] * 64 + lane];
        ax += bflo(v); ay += bfhi(v);
      }
      ax += bx + cx + dx; ay += by + cy + dy;
    }
    // wave-private row write (64 lanes x 4B consecutive: conflict-free)
    *reinterpret_cast<unsigned int*>(&Zbuf[(wrow0 + n) * LDK + lane * 2]) =
        (unsigned)f2bf(ax) | ((unsigned)f2bf(ay) << 16);
  }
  float b1g[8], b2g[8];
#pragma unroll
  for (int ct = 0; ct < 8; ++ct) b1g[ct] = b1[ct * 16 + l15];
  __syncthreads();                                   // Wbuf + Zbuf ready

  // ---- GEMM1: acc = z @ W1 ----
  bf16x8 a[4];
#pragma unroll
  for (int ks = 0; ks < 4; ++ks)
    a[ks] = *reinterpret_cast<const bf16x8*>(&Zbuf[(wrow0 + l15) * LDK + ks * 32 + lg * 8]);
  f32x4 acc[8];
#pragma unroll
  for (int ct = 0; ct < 8; ++ct) {
    acc[ct] = (f32x4){0.f, 0.f, 0.f, 0.f};
#pragma unroll
    for (int ks = 0; ks < 4; ++ks) {
      bf16x8 b = *reinterpret_cast<const bf16x8*>(
          &Wbuf[(ct * 16 + l15) * LDK + ks * 32 + lg * 8]);
      acc[ct] = __builtin_amdgcn_mfma_f32_16x16x32_bf16(a[ks], b, acc[ct], 0, 0, 0);
    }
  }

  // t = relu(acc+b1) -> Zbuf (bf16). Wave-private rows: no barrier needed.
#pragma unroll
  for (int ct = 0; ct < 8; ++ct) {
#pragma unroll
    for (int r = 0; r < 4; ++r) {
      float v = fmaxf(acc[ct][r] + b1g[ct], 0.f);
      Zbuf[(wrow0 + lg * 4 + r) * LDK + ct * 16 + l15] = f2bf(v);
    }
  }
  __syncthreads();                                   // all GEMM1 Wbuf reads done

  {  // re-stage Wbuf with Wt2; zero pool accumulator
    const u16x8* wsrc = reinterpret_cast<const u16x8*>(wt2);
#pragma unroll
    for (int i = 0; i < 4; ++i) {
      int g = tid + i * 512;
      *reinterpret_cast<u16x8*>(&Wbuf[(g >> 4) * LDK + (g & 15) * 8]) = wsrc[g];
    }
    if (tid < HID) pool_shf[tid] = 0.f;
#pragma unroll
    for (int ct = 0; ct < 8; ++ct) b2g[ct] = b2[ct * 16 + l15];
  }
  __syncthreads();

  // ---- GEMM2: acc = t @ W2 ----
#pragma unroll
  for (int ks = 0; ks < 4; ++ks)
    a[ks] = *reinterpret_cast<const bf16x8*>(&Zbuf[(wrow0 + l15) * LDK + ks * 32 + lg * 8]);
#pragma unroll
  for (int ct = 0; ct < 8; ++ct) {
    acc[ct] = (f32x4){0.f, 0.f, 0.f, 0.f};
#pragma unroll
    for (int ks = 0; ks < 4; ++ks) {
      bf16x8 b = *reinterpret_cast<const bf16x8*>(
          &Wbuf[(ct * 16 + l15) * LDK + ks * 32 + lg * 8]);
      acc[ct] = __builtin_amdgcn_mfma_f32_16x16x32_bf16(a[ks], b, acc[ct], 0, 0, 0);
    }
  }

  // ---- epilogue: hv = relu(acc+b2)*imp; pool from regs; optional h store ----
  float impv[4];
  int glane[4];
#pragma unroll
  for (int r = 0; r < 4; ++r) {
    int row = row0 + wrow0 + lg * 4 + r;
    bool ok = row < N_NODES;
    impv[r] = ok ? imp[row] : 0.f;
    glane[r] = ok ? batch[row] : -1;
  }
#pragma unroll
  for (int ct = 0; ct < 8; ++ct) {
#pragma unroll
    for (int r = 0; r < 4; ++r) {
      float hv = fmaxf(acc[ct][r] + b2g[ct], 0.f) * impv[r];
      acc[ct][r] = hv;
      if (store_h)   // wave-private row; uniform branch
        Zbuf[(wrow0 + lg * 4 + r) * LDK + ct * 16 + l15] = f2bf(hv);
    }
  }
  const int rlast = min(row0 + 127, N_NODES - 1);
  const int g0 = batch[row0];
  const bool uniform = (batch[rlast] == g0);         // block-uniform predicate

  if (uniform) {
#pragma unroll
    for (int ct = 0; ct < 8; ++ct) {
      float val = acc[ct][0] + acc[ct][1] + acc[ct][2] + acc[ct][3];
      val += __shfl_xor(val, 16, 64);                // combine 4 lane-groups
      val += __shfl_xor(val, 32, 64);
      if (lane < 16) atomicAdd(&pool_shf[ct * 16 + l15], val);
    }
  } else {
    const int glast = batch[rlast];
    for (int g = g0; g <= glast; ++g) {              // few graphs per boundary chunk
#pragma unroll
      for (int ct = 0; ct < 8; ++ct) {
        float val = 0.f;
#pragma unroll
        for (int r = 0; r < 4; ++r)
          if (glane[r] == g) val += acc[ct][r];
        val += __shfl_xor(val, 16, 64);
        val += __shfl_xor(val, 32, 64);
        if (lane < 16)
          atomicAdd(out + (size_t)g * (N_LAYERS * HID) + lofs + ct * 16 + l15, val);
      }
    }
  }
  __syncthreads();                                   // h in Zbuf + pool_shf ready

  if (store_h) {  // coalesced bf16 h store (16B per thread-chunk)
#pragma unroll
    for (int i = 0; i < 4; ++i) {
      int g = tid + i * 512;
      int r = g >> 4, kc = g & 15;
      if (row0 + r < N_NODES)
        hout[(size_t)(row0 + r) * 16 + kc] =
            *reinterpret_cast<const u16x8*>(&Zbuf[r * LDK + kc * 8]);
    }
  }
  if (uniform && tid < HID)
    atomicAdd(out + (size_t)g0 * (N_LAYERS * HID) + lofs + tid, pool_shf[tid]);
}

extern "C" void kernel_launch(void* const* d_in, const int* in_sizes, int n_in,
                              void* d_out, int out_size, void* d_ws, size_t ws_size,
                              hipStream_t stream) {
  const float* x    = (const float*)d_in[0];
  const int*   ei   = (const int*)d_in[1];          // [2, N_EDGES]
  const int*   batch= (const int*)d_in[2];
  const float* imp  = (const float*)d_in[3];
  const float* W1   = (const float*)d_in[4];        // [3,128,128]
  const float* b1   = (const float*)d_in[5];        // [3,128]
  const float* W2   = (const float*)d_in[6];
  const float* b2   = (const float*)d_in[7];
  float* out = (float*)d_out;                       // [64, 384]

  const int* src = ei;
  const int* dst = ei + N_EDGES;

  // workspace layout (all 16B-aligned)
  char* w = (char*)d_ws;
  unsigned int* hb0 = (unsigned int*)w; w += (size_t)N_NODES * 64 * sizeof(int);  // 12.8MB
  unsigned int* hb1 = (unsigned int*)w; w += (size_t)N_NODES * 64 * sizeof(int);  // 12.8MB
  unsigned short* wt = (unsigned short*)w; w += (size_t)6 * HID * HID * sizeof(short);
  int* esrc   = (int*)w;            w += (size_t)N_EDGES * sizeof(int);           // 2.4MB
  int* deg    = (int*)w;            w += (size_t)DEG_PAD * sizeof(int);
  int* bsum   = (int*)w;            w += 64 * sizeof(int);
  int* boff   = (int*)w;            w += 64 * sizeof(int);
  int* cursor = (int*)w;            w += (size_t)N_NODES * sizeof(int);
  int* rowptr = (int*)w;            w += ((size_t)N_NODES + 1) * sizeof(int);

  hipMemsetAsync(out, 0, (size_t)N_GRAPHS * N_LAYERS * HID * sizeof(float), stream);
  hipMemsetAsync(deg, 0, (size_t)DEG_PAD * sizeof(int), stream);

  scale_kernel<<<(N_NODES * 32 + 255) / 256, 256, 0, stream>>>(x, imp, hb0);
  wconv_kernel<<<6, 256, 0, stream>>>(W1, W2, wt);
  hist_kernel<<<(N_EDGES + 255) / 256, 256, 0, stream>>>(dst, deg);
  scan1_kernel<<<SCAN_BLOCKS, 256, 0, stream>>>(deg, bsum);
  scan2_kernel<<<1, 64, 0, stream>>>(bsum, boff);
  scan3_kernel<<<SCAN_BLOCKS, 256, 0, stream>>>(deg, boff, rowptr, cursor);
  scatter_kernel<<<(N_EDGES + 255) / 256, 256, 0, stream>>>(src, dst, cursor, esrc);

  const int grid = (N_NODES + 127) / 128;           // 391 chunks
  // h ping-pong: l0 hb0->hb1, l1 hb1->hb0, l2 hb0->(skip)
  const unsigned int* hin[3] = {hb0, hb1, hb0};
  unsigned int* hout[3] = {hb1, hb0, hb1};
  for (int l = 0; l < N_LAYERS; ++l) {
    layer_kernel<<<grid, 512, 0, stream>>>(
        hin[l], rowptr, esrc,
        wt + (size_t)l * HID * HID, b1 + (size_t)l * HID,
        wt + (size_t)(3 + l) * HID * HID, b2 + (size_t)l * HID,
        imp, batch, (u16x8*)hout[l], out, l * HID,
        (l < N_LAYERS - 1) ? 1 : 0);
  }
}

// Round 10
// 277.448 us; speedup vs baseline: 1.2722x; 1.2722x over previous
//
#include <hip/hip_runtime.h>
#include <hip/hip_bf16.h>

#define N_NODES 50000
#define N_EDGES 600000
#define HID 128
#define N_LAYERS 3
#define N_GRAPHS 64
#define DEG_PAD 53248       // 52 blocks * 256 thr * 4 ints, zero-padded
#define SCAN_BLOCKS 52
#define LDK 136             // padded k-stride (bf16): 272B row ≡ 4 banks mod 32

typedef __attribute__((ext_vector_type(8))) short bf16x8;        // MFMA A/B frag
typedef __attribute__((ext_vector_type(8))) unsigned short u16x8; // 16B chunks
typedef __attribute__((ext_vector_type(4))) float f32x4;         // MFMA C/D frag

__device__ __forceinline__ unsigned short f2bf(float v) {
  __hip_bfloat16 b = __float2bfloat16(v);   // RNE
  unsigned short u;
  __builtin_memcpy(&u, &b, 2);
  return u;
}
__device__ __forceinline__ float bflo(unsigned int v) {
  unsigned int u = v << 16; float f; __builtin_memcpy(&f, &u, 4); return f;
}
__device__ __forceinline__ float bfhi(unsigned int v) {
  unsigned int u = v & 0xFFFF0000u; float f; __builtin_memcpy(&f, &u, 4); return f;
}

// ---------------- hb = bf16(x * node_imp), packed 2/uint ----------------
__global__ __launch_bounds__(256) void scale_kernel(const float* __restrict__ x,
                                                    const float* __restrict__ imp,
                                                    unsigned int* __restrict__ hb) {
  int i = blockIdx.x * 256 + threadIdx.x;            // over N_NODES*32 float4
  if (i >= N_NODES * (HID / 4)) return;
  float s = imp[i >> 5];
  float4 v = reinterpret_cast<const float4*>(x)[i];
  uint2 p;
  p.x = (unsigned)f2bf(v.x * s) | ((unsigned)f2bf(v.y * s) << 16);
  p.y = (unsigned)f2bf(v.z * s) | ((unsigned)f2bf(v.w * s) << 16);
  reinterpret_cast<uint2*>(hb)[i] = p;
}

// ---------------- W pre-convert: f32 [k][n] -> bf16 Wt [n][k] ----------------
__global__ __launch_bounds__(256) void wconv_kernel(const float* __restrict__ W1,
                                                    const float* __restrict__ W2,
                                                    unsigned short* __restrict__ wt) {
  const int m = blockIdx.x;                          // 0..5
  const float* src = (m < 3) ? (W1 + (size_t)m * HID * HID)
                             : (W2 + (size_t)(m - 3) * HID * HID);
  unsigned short* dst = wt + (size_t)m * HID * HID;
  const int tid = threadIdx.x;
  const int n = tid >> 1, kh = (tid & 1) * 64;
#pragma unroll 8
  for (int k = 0; k < 64; ++k)
    dst[n * HID + kh + k] = f2bf(src[(kh + k) * HID + n]);
}

// ---------------- CSR build: histogram ----------------
__global__ __launch_bounds__(256) void hist_kernel(const int* __restrict__ dst,
                                                   int* __restrict__ deg) {
  int e = blockIdx.x * 256 + threadIdx.x;
  if (e < N_EDGES) atomicAdd(&deg[dst[e]], 1);
}

// ------------- CSR scan, 3-kernel hierarchical (coalesced int4) -------------
__global__ __launch_bounds__(256) void scan1_kernel(const int* __restrict__ deg,
                                                    int* __restrict__ bsum) {
  int t = blockIdx.x * 256 + threadIdx.x;
  int4 d = reinterpret_cast<const int4*>(deg)[t];
  int s = d.x + d.y + d.z + d.w;
#pragma unroll
  for (int off = 1; off < 64; off <<= 1) s += __shfl_xor(s, off, 64);
  __shared__ int ws[4];
  if ((threadIdx.x & 63) == 0) ws[threadIdx.x >> 6] = s;
  __syncthreads();
  if (threadIdx.x == 0) bsum[blockIdx.x] = ws[0] + ws[1] + ws[2] + ws[3];
}

__global__ __launch_bounds__(64) void scan2_kernel(const int* __restrict__ bsum,
                                                   int* __restrict__ boff) {
  int t = threadIdx.x;                               // one wave
  int v = (t < SCAN_BLOCKS) ? bsum[t] : 0;
  int incl = v;
#pragma unroll
  for (int off = 1; off < 64; off <<= 1) {
    int u = __shfl_up(incl, off, 64);
    if (t >= off) incl += u;
  }
  if (t < SCAN_BLOCKS) boff[t] = incl - v;           // exclusive
}

__global__ __launch_bounds__(256) void scan3_kernel(const int* __restrict__ deg,
                                                    const int* __restrict__ boff,
                                                    int* __restrict__ rowptr,
                                                    int* __restrict__ cursor) {
  const int t = blockIdx.x * 256 + threadIdx.x;
  const int lane = threadIdx.x & 63, wid = threadIdx.x >> 6;
  int4 d = reinterpret_cast<const int4*>(deg)[t];
  int tsum = d.x + d.y + d.z + d.w;
  int incl = tsum;
#pragma unroll
  for (int off = 1; off < 64; off <<= 1) {
    int u = __shfl_up(incl, off, 64);
    if (lane >= off) incl += u;
  }
  __shared__ int wsum[4], wpre[4];
  if (lane == 63) wsum[wid] = incl;
  __syncthreads();
  if (threadIdx.x == 0) {
    int c = 0;
#pragma unroll
    for (int i = 0; i < 4; ++i) { wpre[i] = c; c += wsum[i]; }
  }
  __syncthreads();
  int run = boff[blockIdx.x] + wpre[wid] + (incl - tsum);
  int e1 = run + d.x, e2 = e1 + d.y, e3 = e2 + d.z, e4 = e3 + d.w;
  int base = t * 4;                                  // N_NODES % 4 == 0
  if (base < N_NODES) {
    reinterpret_cast<int4*>(cursor)[t] = make_int4(run, e1, e2, e3);
    rowptr[base + 1] = e1; rowptr[base + 2] = e2;
    rowptr[base + 3] = e3; rowptr[base + 4] = e4;
  }
  if (t == 0) rowptr[0] = 0;
}

// ---------------- CSR build: scatter edge sources by dst ----------------
__global__ __launch_bounds__(256) void scatter_kernel(const int* __restrict__ src,
                                                      const int* __restrict__ dst,
                                                      int* __restrict__ cursor,
                                                      int* __restrict__ esrc) {
  int e = blockIdx.x * 256 + threadIdx.x;
  if (e >= N_EDGES) return;
  int pos = atomicAdd(&cursor[dst[e]], 1);
  esrc[pos] = src[e];
}

// 8 gather loads, optionally masked (uniform mask per k as 0/1 fma multiplier)
#define GATH8(IDXK)                                                            \
  {                                                                            \
    unsigned v0 = hb_[(size_t)(unsigned)__builtin_amdgcn_readlane((int)ev, IDXK(0)) * 64 + lane]; \
    unsigned v1 = hb_[(size_t)(unsigned)__builtin_amdgcn_readlane((int)ev, IDXK(1)) * 64 + lane]; \
    unsigned v2 = hb_[(size_t)(unsigned)__builtin_amdgcn_readlane((int)ev, IDXK(2)) * 64 + lane]; \
    unsigned v3 = hb_[(size_t)(unsigned)__builtin_amdgcn_readlane((int)ev, IDXK(3)) * 64 + lane]; \
    unsigned v4 = hb_[(size_t)(unsigned)__builtin_amdgcn_readlane((int)ev, IDXK(4)) * 64 + lane]; \
    unsigned v5 = hb_[(size_t)(unsigned)__builtin_amdgcn_readlane((int)ev, IDXK(5)) * 64 + lane]; \
    unsigned v6 = hb_[(size_t)(unsigned)__builtin_amdgcn_readlane((int)ev, IDXK(6)) * 64 + lane]; \
    unsigned v7 = hb_[(size_t)(unsigned)__builtin_amdgcn_readlane((int)ev, IDXK(7)) * 64 + lane]; \
    MASKADD(0, v0) MASKADD(1, v1) MASKADD(2, v2) MASKADD(3, v3)                \
    MASKADD(4, v4) MASKADD(5, v5) MASKADD(6, v6) MASKADD(7, v7)                \
  }

// ---------------- fused layer: gather + MFMA MLP + h-update + pool ----------
// 512 thr = 8 waves; chunk = 128 rows; wave w owns rows [w*16, w*16+16).
// Gather de-serialized: rowptr window preloaded (17 lanes), per-node edge
// indices batch-loaded (64/coalesced load) and broadcast via readlane,
// next node's batch+self prefetched before current node's loads, 8-deep
// independent accumulators with masked final block. W1 staged T14-style
// (global->reg at start, reg->LDS after gather).
__global__ __launch_bounds__(512, 4) void layer_kernel(
    const unsigned int* __restrict__ hin, const int* __restrict__ rowptr,
    const int* __restrict__ esrc, const unsigned short* __restrict__ wt1,
    const float* __restrict__ b1, const unsigned short* __restrict__ wt2,
    const float* __restrict__ b2, const float* __restrict__ imp,
    const int* __restrict__ batch, u16x8* __restrict__ hout,
    float* __restrict__ out, int lofs, int store_h) {
  __shared__ unsigned short Wbuf[128 * LDK];
  __shared__ unsigned short Zbuf[128 * LDK];
  __shared__ float pool_shf[HID];

  const int tid = threadIdx.x;
  const int lane = tid & 63;
  const int l15 = lane & 15, lg = lane >> 4;
  const int wrow0 = (tid >> 6) * 16;                 // wave's 16-row stripe
  const int row0 = blockIdx.x << 7;                  // chunk base
  const unsigned int* hb_ = hin;

  // Phase A: issue Wt1 loads into regs (LDS write deferred past gather)
  u16x8 wreg[4];
  {
    const u16x8* wsrc = reinterpret_cast<const u16x8*>(wt1);
#pragma unroll
    for (int i = 0; i < 4; ++i) wreg[i] = wsrc[tid + i * 512];
  }

  // Phase B: gather this wave's 16 nodes
  {
    const int nbase = row0 + wrow0;
    // rowptr window: lanes 0..16 hold rowptr[nbase .. nbase+16]
    int rpv = rowptr[min(nbase + min(lane, 16), N_NODES)];
    int s_cur = __builtin_amdgcn_readlane(rpv, 0);
    int e_cur = __builtin_amdgcn_readlane(rpv, 1);
    unsigned ev_cur = 0, self_cur = 0;
    {
      int c0 = min(e_cur - s_cur, 64);
      if (lane < c0) ev_cur = (unsigned)esrc[s_cur + lane];
      if (nbase < N_NODES) self_cur = hb_[(size_t)nbase * 64 + lane];
    }
#pragma unroll 1
    for (int n = 0; n < 16; ++n) {
      const int s = s_cur, e = e_cur;
      const unsigned self = self_cur;
      unsigned ev = ev_cur;
      // prefetch next node's first index batch + self row
      if (n < 15) {
        s_cur = __builtin_amdgcn_readlane(rpv, n + 1);
        e_cur = __builtin_amdgcn_readlane(rpv, n + 2);
        int cn = min(e_cur - s_cur, 64);
        unsigned evn = 0, sn = 0;
        if (lane < cn) evn = (unsigned)esrc[s_cur + lane];
        if (row0 + wrow0 + n + 1 < N_NODES)
          sn = hb_[(size_t)(row0 + wrow0 + n + 1) * 64 + lane];
        ev_cur = evn; self_cur = sn;
      }
      float a0x = bflo(self), a0y = bfhi(self);
      float a1x = 0.f, a1y = 0.f, a2x = 0.f, a2y = 0.f, a3x = 0.f, a3y = 0.f;
      float a4x = 0.f, a4y = 0.f, a5x = 0.f, a5y = 0.f, a6x = 0.f, a6y = 0.f;
      float a7x = 0.f, a7y = 0.f;
      int soff = s, rem = e - s;
#pragma unroll 1
      while (rem > 0) {
        const int cnt = min(rem, 64);
        int i = 0;
#define MASKADD(K, V) a##K##x += bflo(V); a##K##y += bfhi(V);
#define IDXF(K) (i + K)
#pragma unroll 1
        for (; i + 8 <= cnt; i += 8) GATH8(IDXF)
#undef MASKADD
#undef IDXF
        if (i < cnt) {   // masked final block (uniform masks)
#define MASKADD(K, V)                                                          \
          { float m = (i + K < cnt) ? 1.f : 0.f;                               \
            a##K##x = fmaf(m, bflo(V), a##K##x);                               \
            a##K##y = fmaf(m, bfhi(V), a##K##y); }
#define IDXC(K) min(i + K, 63)
          GATH8(IDXC)
#undef MASKADD
#undef IDXC
        }
        soff += cnt; rem -= cnt;
        if (rem > 0) {
          ev = 0;
          if (lane < min(rem, 64)) ev = (unsigned)esrc[soff + lane];
        }
      }
      a0x += a1x + a2x + a3x; a4x += a5x + a6x + a7x; a0x += a4x;
      a0y += a1y + a2y + a3y; a4y += a5y + a6y + a7y; a0y += a4y;
      // wave-private row write (64 lanes x 4B consecutive: conflict-free)
      *reinterpret_cast<unsigned int*>(&Zbuf[(wrow0 + n) * LDK + lane * 2]) =
          (unsigned)f2bf(a0x) | ((unsigned)f2bf(a0y) << 16);
    }
  }

  // Phase C: write staged W1 to LDS
#pragma unroll
  for (int i = 0; i < 4; ++i) {
    int g = tid + i * 512;
    *reinterpret_cast<u16x8*>(&Wbuf[(g >> 4) * LDK + (g & 15) * 8]) = wreg[i];
  }
  float b1g[8], b2g[8];
#pragma unroll
  for (int ct = 0; ct < 8; ++ct) b1g[ct] = b1[ct * 16 + l15];
  __syncthreads();                                   // Wbuf + Zbuf ready

  // ---- GEMM1: acc = z @ W1 ----
  bf16x8 a[4];
#pragma unroll
  for (int ks = 0; ks < 4; ++ks)
    a[ks] = *reinterpret_cast<const bf16x8*>(&Zbuf[(wrow0 + l15) * LDK + ks * 32 + lg * 8]);
  f32x4 acc[8];
#pragma unroll
  for (int ct = 0; ct < 8; ++ct) {
    acc[ct] = (f32x4){0.f, 0.f, 0.f, 0.f};
#pragma unroll
    for (int ks = 0; ks < 4; ++ks) {
      bf16x8 b = *reinterpret_cast<const bf16x8*>(
          &Wbuf[(ct * 16 + l15) * LDK + ks * 32 + lg * 8]);
      acc[ct] = __builtin_amdgcn_mfma_f32_16x16x32_bf16(a[ks], b, acc[ct], 0, 0, 0);
    }
  }

  // t = relu(acc+b1) -> Zbuf (bf16). Wave-private rows: no barrier needed.
#pragma unroll
  for (int ct = 0; ct < 8; ++ct) {
#pragma unroll
    for (int r = 0; r < 4; ++r) {
      float v = fmaxf(acc[ct][r] + b1g[ct], 0.f);
      Zbuf[(wrow0 + lg * 4 + r) * LDK + ct * 16 + l15] = f2bf(v);
    }
  }
  __syncthreads();                                   // all GEMM1 Wbuf reads done

  {  // re-stage Wbuf with Wt2; zero pool accumulator
    const u16x8* wsrc = reinterpret_cast<const u16x8*>(wt2);
#pragma unroll
    for (int i = 0; i < 4; ++i) {
      int g = tid + i * 512;
      *reinterpret_cast<u16x8*>(&Wbuf[(g >> 4) * LDK + (g & 15) * 8]) = wsrc[g];
    }
    if (tid < HID) pool_shf[tid] = 0.f;
#pragma unroll
    for (int ct = 0; ct < 8; ++ct) b2g[ct] = b2[ct * 16 + l15];
  }
  __syncthreads();

  // ---- GEMM2: acc = t @ W2 ----
#pragma unroll
  for (int ks = 0; ks < 4; ++ks)
    a[ks] = *reinterpret_cast<const bf16x8*>(&Zbuf[(wrow0 + l15) * LDK + ks * 32 + lg * 8]);
#pragma unroll
  for (int ct = 0; ct < 8; ++ct) {
    acc[ct] = (f32x4){0.f, 0.f, 0.f, 0.f};
#pragma unroll
    for (int ks = 0; ks < 4; ++ks) {
      bf16x8 b = *reinterpret_cast<const bf16x8*>(
          &Wbuf[(ct * 16 + l15) * LDK + ks * 32 + lg * 8]);
      acc[ct] = __builtin_amdgcn_mfma_f32_16x16x32_bf16(a[ks], b, acc[ct], 0, 0, 0);
    }
  }

  // ---- epilogue: hv = relu(acc+b2)*imp; pool from regs; optional h store ----
  float impv[4];
  int glane[4];
#pragma unroll
  for (int r = 0; r < 4; ++r) {
    int row = row0 + wrow0 + lg * 4 + r;
    bool ok = row < N_NODES;
    impv[r] = ok ? imp[row] : 0.f;
    glane[r] = ok ? batch[row] : -1;
  }
#pragma unroll
  for (int ct = 0; ct < 8; ++ct) {
#pragma unroll
    for (int r = 0; r < 4; ++r) {
      float hv = fmaxf(acc[ct][r] + b2g[ct], 0.f) * impv[r];
      acc[ct][r] = hv;
      if (store_h)   // wave-private row; uniform branch
        Zbuf[(wrow0 + lg * 4 + r) * LDK + ct * 16 + l15] = f2bf(hv);
    }
  }
  const int rlast = min(row0 + 127, N_NODES - 1);
  const int g0 = batch[row0];
  const bool uniform = (batch[rlast] == g0);         // block-uniform predicate

  if (uniform) {
#pragma unroll
    for (int ct = 0; ct < 8; ++ct) {
      float val = acc[ct][0] + acc[ct][1] + acc[ct][2] + acc[ct][3];
      val += __shfl_xor(val, 16, 64);                // combine 4 lane-groups
      val += __shfl_xor(val, 32, 64);
      if (lane < 16) atomicAdd(&pool_shf[ct * 16 + l15], val);
    }
  } else {
    const int glast = batch[rlast];
    for (int g = g0; g <= glast; ++g) {              // few graphs per boundary chunk
#pragma unroll
      for (int ct = 0; ct < 8; ++ct) {
        float val = 0.f;
#pragma unroll
        for (int r = 0; r < 4; ++r)
          if (glane[r] == g) val += acc[ct][r];
        val += __shfl_xor(val, 16, 64);
        val += __shfl_xor(val, 32, 64);
        if (lane < 16)
          atomicAdd(out + (size_t)g * (N_LAYERS * HID) + lofs + ct * 16 + l15, val);
      }
    }
  }
  __syncthreads();                                   // h in Zbuf + pool_shf ready

  if (store_h) {  // coalesced bf16 h store (16B per thread-chunk)
#pragma unroll
    for (int i = 0; i < 4; ++i) {
      int g = tid + i * 512;
      int r = g >> 4, kc = g & 15;
      if (row0 + r < N_NODES)
        hout[(size_t)(row0 + r) * 16 + kc] =
            *reinterpret_cast<const u16x8*>(&Zbuf[r * LDK + kc * 8]);
    }
  }
  if (uniform && tid < HID)
    atomicAdd(out + (size_t)g0 * (N_LAYERS * HID) + lofs + tid, pool_shf[tid]);
}

extern "C" void kernel_launch(void* const* d_in, const int* in_sizes, int n_in,
                              void* d_out, int out_size, void* d_ws, size_t ws_size,
                              hipStream_t stream) {
  const float* x    = (const float*)d_in[0];
  const int*   ei   = (const int*)d_in[1];          // [2, N_EDGES]
  const int*   batch= (const int*)d_in[2];
  const float* imp  = (const float*)d_in[3];
  const float* W1   = (const float*)d_in[4];        // [3,128,128]
  const float* b1   = (const float*)d_in[5];        // [3,128]
  const float* W2   = (const float*)d_in[6];
  const float* b2   = (const float*)d_in[7];
  float* out = (float*)d_out;                       // [64, 384]

  const int* src = ei;
  const int* dst = ei + N_EDGES;

  // workspace layout (all 16B-aligned)
  char* w = (char*)d_ws;
  unsigned int* hb0 = (unsigned int*)w; w += (size_t)N_NODES * 64 * sizeof(int);  // 12.8MB
  unsigned int* hb1 = (unsigned int*)w; w += (size_t)N_NODES * 64 * sizeof(int);  // 12.8MB
  unsigned short* wt = (unsigned short*)w; w += (size_t)6 * HID * HID * sizeof(short);
  int* esrc   = (int*)w;            w += (size_t)N_EDGES * sizeof(int);           // 2.4MB
  int* deg    = (int*)w;            w += (size_t)DEG_PAD * sizeof(int);
  int* bsum   = (int*)w;            w += 64 * sizeof(int);
  int* boff   = (int*)w;            w += 64 * sizeof(int);
  int* cursor = (int*)w;            w += (size_t)N_NODES * sizeof(int);
  int* rowptr = (int*)w;            w += ((size_t)N_NODES + 1) * sizeof(int);

  hipMemsetAsync(out, 0, (size_t)N_GRAPHS * N_LAYERS * HID * sizeof(float), stream);
  hipMemsetAsync(deg, 0, (size_t)DEG_PAD * sizeof(int), stream);

  scale_kernel<<<(N_NODES * 32 + 255) / 256, 256, 0, stream>>>(x, imp, hb0);
  wconv_kernel<<<6, 256, 0, stream>>>(W1, W2, wt);
  hist_kernel<<<(N_EDGES + 255) / 256, 256, 0, stream>>>(dst, deg);
  scan1_kernel<<<SCAN_BLOCKS, 256, 0, stream>>>(deg, bsum);
  scan2_kernel<<<1, 64, 0, stream>>>(bsum, boff);
  scan3_kernel<<<SCAN_BLOCKS, 256, 0, stream>>>(deg, boff, rowptr, cursor);
  scatter_kernel<<<(N_EDGES + 255) / 256, 256, 0, stream>>>(src, dst, cursor, esrc);

  const int grid = (N_NODES + 127) / 128;           // 391 chunks
  // h ping-pong: l0 hb0->hb1, l1 hb1->hb0, l2 hb0->(skip)
  const unsigned int* hin[3] = {hb0, hb1, hb0};
  unsigned int* hout[3] = {hb1, hb0, hb1};
  for (int l = 0; l < N_LAYERS; ++l) {
    layer_kernel<<<grid, 512, 0, stream>>>(
        hin[l], rowptr, esrc,
        wt + (size_t)l * HID * HID, b1 + (size_t)l * HID,
        wt + (size_t)(3 + l) * HID * HID, b2 + (size_t)l * HID,
        imp, batch, (u16x8*)hout[l], out, l * HID,
        (l < N_LAYERS - 1) ? 1 : 0);
  }
}

// Round 12
// 267.434 us; speedup vs baseline: 1.3198x; 1.0374x over previous
//
#include <hip/hip_runtime.h>
#include <hip/hip_bf16.h>

#define N_NODES 50000
#define N_EDGES 600000
#define HID 128
#define N_LAYERS 3
#define N_GRAPHS 64
#define DEG_PAD 53248       // 52 scan-blocks * 256 thr * 4 ints, zero-padded
#define SCAN_BLOCKS 52
#define LDK 136             // padded k-stride (bf16): 272B row ≡ 4 banks mod 32

typedef __attribute__((ext_vector_type(8))) short bf16x8;        // MFMA A/B frag
typedef __attribute__((ext_vector_type(8))) unsigned short u16x8; // 16B chunks
typedef __attribute__((ext_vector_type(4))) float f32x4;         // MFMA C/D frag

__device__ __forceinline__ unsigned short f2bf(float v) {
  __hip_bfloat16 b = __float2bfloat16(v);   // RNE
  unsigned short u;
  __builtin_memcpy(&u, &b, 2);
  return u;
}
__device__ __forceinline__ float bflo(unsigned int v) {
  unsigned int u = v << 16; float f; __builtin_memcpy(&f, &u, 4); return f;
}
__device__ __forceinline__ float bfhi(unsigned int v) {
  unsigned int u = v & 0xFFFF0000u; float f; __builtin_memcpy(&f, &u, 4); return f;
}

// -------- prep: zero deg+out, scale x->hb0 (bf16x2), wconv W->wt (bf16^T) ----
__global__ __launch_bounds__(256) void prep_kernel(
    const float* __restrict__ x, const float* __restrict__ imp,
    const float* __restrict__ W1, const float* __restrict__ W2,
    unsigned int* __restrict__ hb, unsigned short* __restrict__ wt,
    int* __restrict__ deg, float* __restrict__ out) {
  const int gtid = blockIdx.x * 256 + threadIdx.x;
  const int gsz = gridDim.x * 256;
  for (int i = gtid; i < DEG_PAD / 4; i += gsz)
    reinterpret_cast<int4*>(deg)[i] = make_int4(0, 0, 0, 0);
  for (int i = gtid; i < (N_GRAPHS * N_LAYERS * HID) / 4; i += gsz)
    reinterpret_cast<float4*>(out)[i] = make_float4(0.f, 0.f, 0.f, 0.f);
  for (int i = gtid; i < N_NODES * (HID / 4); i += gsz) {
    float s = imp[i >> 5];
    float4 v = reinterpret_cast<const float4*>(x)[i];
    uint2 p;
    p.x = (unsigned)f2bf(v.x * s) | ((unsigned)f2bf(v.y * s) << 16);
    p.y = (unsigned)f2bf(v.z * s) | ((unsigned)f2bf(v.w * s) << 16);
    reinterpret_cast<uint2*>(hb)[i] = p;
  }
  for (int i = gtid; i < 6 * HID * HID; i += gsz) {
    int m = i >> 14, r = i & 16383, n = r >> 7, k = r & 127;
    const float* s_ = (m < 3) ? (W1 + (size_t)m * HID * HID)
                              : (W2 + (size_t)(m - 3) * HID * HID);
    wt[(size_t)m * HID * HID + n * HID + k] = f2bf(s_[k * HID + n]);
  }
}

// ---------------- CSR build: histogram ----------------
__global__ __launch_bounds__(256) void hist_kernel(const int* __restrict__ dst,
                                                   int* __restrict__ deg) {
  int e = blockIdx.x * 256 + threadIdx.x;
  if (e < N_EDGES) atomicAdd(&deg[dst[e]], 1);
}

// ------------- CSR scan, 2-kernel hierarchical (coalesced int4) -------------
__global__ __launch_bounds__(256) void scan1_kernel(const int* __restrict__ deg,
                                                    int* __restrict__ bsum) {
  int t = blockIdx.x * 256 + threadIdx.x;
  int4 d = reinterpret_cast<const int4*>(deg)[t];
  int s = d.x + d.y + d.z + d.w;
#pragma unroll
  for (int off = 1; off < 64; off <<= 1) s += __shfl_xor(s, off, 64);
  __shared__ int ws[4];
  if ((threadIdx.x & 63) == 0) ws[threadIdx.x >> 6] = s;
  __syncthreads();
  if (threadIdx.x == 0) bsum[blockIdx.x] = ws[0] + ws[1] + ws[2] + ws[3];
}

// scan3: each block derives its own offset from bsum (masked wave reduce),
// then writes rowptr + cursor. Replaces R10's scan2+scan3 pair.
__global__ __launch_bounds__(256) void scan3_kernel(const int* __restrict__ deg,
                                                    const int* __restrict__ bsum,
                                                    int* __restrict__ rowptr,
                                                    int* __restrict__ cursor) {
  const int t = blockIdx.x * 256 + threadIdx.x;
  const int lane = threadIdx.x & 63, wid = threadIdx.x >> 6;
  __shared__ int boff_sh;
  if (threadIdx.x < 64) {                            // wave 0: sum bsum[j < bid]
    int v = (lane < (int)blockIdx.x && lane < SCAN_BLOCKS) ? bsum[lane] : 0;
#pragma unroll
    for (int off = 1; off < 64; off <<= 1) v += __shfl_xor(v, off, 64);
    if (lane == 0) boff_sh = v;
  }
  int4 d = reinterpret_cast<const int4*>(deg)[t];
  int tsum = d.x + d.y + d.z + d.w;
  int incl = tsum;
#pragma unroll
  for (int off = 1; off < 64; off <<= 1) {
    int u = __shfl_up(incl, off, 64);
    if (lane >= off) incl += u;
  }
  __shared__ int wsum[4], wpre[4];
  if (lane == 63) wsum[wid] = incl;
  __syncthreads();
  if (threadIdx.x == 0) {
    int c = 0;
#pragma unroll
    for (int i = 0; i < 4; ++i) { wpre[i] = c; c += wsum[i]; }
  }
  __syncthreads();
  int run = boff_sh + wpre[wid] + (incl - tsum);
  int e1 = run + d.x, e2 = e1 + d.y, e3 = e2 + d.z, e4 = e3 + d.w;
  int base = t * 4;                                  // N_NODES % 4 == 0
  if (base < N_NODES) {
    reinterpret_cast<int4*>(cursor)[t] = make_int4(run, e1, e2, e3);
    rowptr[base + 1] = e1; rowptr[base + 2] = e2;
    rowptr[base + 3] = e3; rowptr[base + 4] = e4;
  }
  if (t == 0) rowptr[0] = 0;
}

// ---------------- CSR build: scatter edge sources by dst ----------------
__global__ __launch_bounds__(256) void scatter_kernel(const int* __restrict__ src,
                                                      const int* __restrict__ dst,
                                                      int* __restrict__ cursor,
                                                      int* __restrict__ esrc) {
  int e = blockIdx.x * 256 + threadIdx.x;
  if (e >= N_EDGES) return;
  int pos = atomicAdd(&cursor[dst[e]], 1);
  esrc[pos] = src[e];
}

// 8 gather loads, optionally masked (uniform mask per k as 0/1 fma multiplier)
#define GATH8(IDXK)                                                            \
  {                                                                            \
    unsigned v0 = hb_[(size_t)(unsigned)__builtin_amdgcn_readlane((int)ev, IDXK(0)) * 64 + lane]; \
    unsigned v1 = hb_[(size_t)(unsigned)__builtin_amdgcn_readlane((int)ev, IDXK(1)) * 64 + lane]; \
    unsigned v2 = hb_[(size_t)(unsigned)__builtin_amdgcn_readlane((int)ev, IDXK(2)) * 64 + lane]; \
    unsigned v3 = hb_[(size_t)(unsigned)__builtin_amdgcn_readlane((int)ev, IDXK(3)) * 64 + lane]; \
    unsigned v4 = hb_[(size_t)(unsigned)__builtin_amdgcn_readlane((int)ev, IDXK(4)) * 64 + lane]; \
    unsigned v5 = hb_[(size_t)(unsigned)__builtin_amdgcn_readlane((int)ev, IDXK(5)) * 64 + lane]; \
    unsigned v6 = hb_[(size_t)(unsigned)__builtin_amdgcn_readlane((int)ev, IDXK(6)) * 64 + lane]; \
    unsigned v7 = hb_[(size_t)(unsigned)__builtin_amdgcn_readlane((int)ev, IDXK(7)) * 64 + lane]; \
    MASKADD(0, v0) MASKADD(1, v1) MASKADD(2, v2) MASKADD(3, v3)                \
    MASKADD(4, v4) MASKADD(5, v5) MASKADD(6, v6) MASKADD(7, v7)                \
  }

// ---------------- fused layer: gather + MFMA MLP + h-update + pool ----------
// (verbatim R10 layer_kernel — passed at 277us, absmax 2.0)
__global__ __launch_bounds__(512, 4) void layer_kernel(
    const unsigned int* __restrict__ hin, const int* __restrict__ rowptr,
    const int* __restrict__ esrc, const unsigned short* __restrict__ wt1,
    const float* __restrict__ b1, const unsigned short* __restrict__ wt2,
    const float* __restrict__ b2, const float* __restrict__ imp,
    const int* __restrict__ batch, u16x8* __restrict__ hout,
    float* __restrict__ out, int lofs, int store_h) {
  __shared__ unsigned short Wbuf[128 * LDK];
  __shared__ unsigned short Zbuf[128 * LDK];
  __shared__ float pool_shf[HID];

  const int tid = threadIdx.x;
  const int lane = tid & 63;
  const int l15 = lane & 15, lg = lane >> 4;
  const int wrow0 = (tid >> 6) * 16;                 // wave's 16-row stripe
  const int row0 = blockIdx.x << 7;                  // chunk base
  const unsigned int* hb_ = hin;

  // Phase A: issue Wt1 loads into regs (LDS write deferred past gather)
  u16x8 wreg[4];
  {
    const u16x8* wsrc = reinterpret_cast<const u16x8*>(wt1);
#pragma unroll
    for (int i = 0; i < 4; ++i) wreg[i] = wsrc[tid + i * 512];
  }

  // Phase B: gather this wave's 16 nodes
  {
    const int nbase = row0 + wrow0;
    // rowptr window: lanes 0..16 hold rowptr[nbase .. nbase+16]
    int rpv = rowptr[min(nbase + min(lane, 16), N_NODES)];
    int s_cur = __builtin_amdgcn_readlane(rpv, 0);
    int e_cur = __builtin_amdgcn_readlane(rpv, 1);
    unsigned ev_cur = 0, self_cur = 0;
    {
      int c0 = min(e_cur - s_cur, 64);
      if (lane < c0) ev_cur = (unsigned)esrc[s_cur + lane];
      if (nbase < N_NODES) self_cur = hb_[(size_t)nbase * 64 + lane];
    }
#pragma unroll 1
    for (int n = 0; n < 16; ++n) {
      const int s = s_cur, e = e_cur;
      const unsigned self = self_cur;
      unsigned ev = ev_cur;
      // prefetch next node's first index batch + self row
      if (n < 15) {
        s_cur = __builtin_amdgcn_readlane(rpv, n + 1);
        e_cur = __builtin_amdgcn_readlane(rpv, n + 2);
        int cn = min(e_cur - s_cur, 64);
        unsigned evn = 0, sn = 0;
        if (lane < cn) evn = (unsigned)esrc[s_cur + lane];
        if (row0 + wrow0 + n + 1 < N_NODES)
          sn = hb_[(size_t)(row0 + wrow0 + n + 1) * 64 + lane];
        ev_cur = evn; self_cur = sn;
      }
      float a0x = bflo(self), a0y = bfhi(self);
      float a1x = 0.f, a1y = 0.f, a2x = 0.f, a2y = 0.f, a3x = 0.f, a3y = 0.f;
      float a4x = 0.f, a4y = 0.f, a5x = 0.f, a5y = 0.f, a6x = 0.f, a6y = 0.f;
      float a7x = 0.f, a7y = 0.f;
      int soff = s, rem = e - s;
#pragma unroll 1
      while (rem > 0) {
        const int cnt = min(rem, 64);
        int i = 0;
#define MASKADD(K, V) a##K##x += bflo(V); a##K##y += bfhi(V);
#define IDXF(K) (i + K)
#pragma unroll 1
        for (; i + 8 <= cnt; i += 8) GATH8(IDXF)
#undef MASKADD
#undef IDXF
        if (i < cnt) {   // masked final block (uniform masks)
#define MASKADD(K, V)                                                          \
          { float m = (i + K < cnt) ? 1.f : 0.f;                               \
            a##K##x = fmaf(m, bflo(V), a##K##x);                               \
            a##K##y = fmaf(m, bfhi(V), a##K##y); }
#define IDXC(K) min(i + K, 63)
          GATH8(IDXC)
#undef MASKADD
#undef IDXC
        }
        soff += cnt; rem -= cnt;
        if (rem > 0) {
          ev = 0;
          if (lane < min(rem, 64)) ev = (unsigned)esrc[soff + lane];
        }
      }
      a0x += a1x + a2x + a3x; a4x += a5x + a6x + a7x; a0x += a4x;
      a0y += a1y + a2y + a3y; a4y += a5y + a6y + a7y; a0y += a4y;
      // wave-private row write (64 lanes x 4B consecutive: conflict-free)
      *reinterpret_cast<unsigned int*>(&Zbuf[(wrow0 + n) * LDK + lane * 2]) =
          (unsigned)f2bf(a0x) | ((unsigned)f2bf(a0y) << 16);
    }
  }

  // Phase C: write staged W1 to LDS
#pragma unroll
  for (int i = 0; i < 4; ++i) {
    int g = tid + i * 512;
    *reinterpret_cast<u16x8*>(&Wbuf[(g >> 4) * LDK + (g & 15) * 8]) = wreg[i];
  }
  float b1g[8], b2g[8];
#pragma unroll
  for (int ct = 0; ct < 8; ++ct) b1g[ct] = b1[ct * 16 + l15];
  __syncthreads();                                   // Wbuf + Zbuf ready

  // ---- GEMM1: acc = z @ W1 ----
  bf16x8 a[4];
#pragma unroll
  for (int ks = 0; ks < 4; ++ks)
    a[ks] = *reinterpret_cast<const bf16x8*>(&Zbuf[(wrow0 + l15) * LDK + ks * 32 + lg * 8]);
  f32x4 acc[8];
#pragma unroll
  for (int ct = 0; ct < 8; ++ct) {
    acc[ct] = (f32x4){0.f, 0.f, 0.f, 0.f};
#pragma unroll
    for (int ks = 0; ks < 4; ++ks) {
      bf16x8 b = *reinterpret_cast<const bf16x8*>(
          &Wbuf[(ct * 16 + l15) * LDK + ks * 32 + lg * 8]);
      acc[ct] = __builtin_amdgcn_mfma_f32_16x16x32_bf16(a[ks], b, acc[ct], 0, 0, 0);
    }
  }

  // t = relu(acc+b1) -> Zbuf (bf16). Wave-private rows: no barrier needed.
#pragma unroll
  for (int ct = 0; ct < 8; ++ct) {
#pragma unroll
    for (int r = 0; r < 4; ++r) {
      float v = fmaxf(acc[ct][r] + b1g[ct], 0.f);
      Zbuf[(wrow0 + lg * 4 + r) * LDK + ct * 16 + l15] = f2bf(v);
    }
  }
  __syncthreads();                                   // all GEMM1 Wbuf reads done

  {  // re-stage Wbuf with Wt2; zero pool accumulator
    const u16x8* wsrc = reinterpret_cast<const u16x8*>(wt2);
#pragma unroll
    for (int i = 0; i < 4; ++i) {
      int g = tid + i * 512;
      *reinterpret_cast<u16x8*>(&Wbuf[(g >> 4) * LDK + (g & 15) * 8]) = wsrc[g];
    }
    if (tid < HID) pool_shf[tid] = 0.f;
#pragma unroll
    for (int ct = 0; ct < 8; ++ct) b2g[ct] = b2[ct * 16 + l15];
  }
  __syncthreads();

  // ---- GEMM2: acc = t @ W2 ----
#pragma unroll
  for (int ks = 0; ks < 4; ++ks)
    a[ks] = *reinterpret_cast<const bf16x8*>(&Zbuf[(wrow0 + l15) * LDK + ks * 32 + lg * 8]);
#pragma unroll
  for (int ct = 0; ct < 8; ++ct) {
    acc[ct] = (f32x4){0.f, 0.f, 0.f, 0.f};
#pragma unroll
    for (int ks = 0; ks < 4; ++ks) {
      bf16x8 b = *reinterpret_cast<const bf16x8*>(
          &Wbuf[(ct * 16 + l15) * LDK + ks * 32 + lg * 8]);
      acc[ct] = __builtin_amdgcn_mfma_f32_16x16x32_bf16(a[ks], b, acc[ct], 0, 0, 0);
    }
  }

  // ---- epilogue: hv = relu(acc+b2)*imp; pool from regs; optional h store ----
  float impv[4];
  int glane[4];
#pragma unroll
  for (int r = 0; r < 4; ++r) {
    int row = row0 + wrow0 + lg * 4 + r;
    bool ok = row < N_NODES;
    impv[r] = ok ? imp[row] : 0.f;
    glane[r] = ok ? batch[row] : -1;
  }
#pragma unroll
  for (int ct = 0; ct < 8; ++ct) {
#pragma unroll
    for (int r = 0; r < 4; ++r) {
      float hv = fmaxf(acc[ct][r] + b2g[ct], 0.f) * impv[r];
      acc[ct][r] = hv;
      if (store_h)   // wave-private row; uniform branch
        Zbuf[(wrow0 + lg * 4 + r) * LDK + ct * 16 + l15] = f2bf(hv);
    }
  }
  const int rlast = min(row0 + 127, N_NODES - 1);
  const int g0 = batch[row0];
  const bool uniform = (batch[rlast] == g0);         // block-uniform predicate

  if (uniform) {
#pragma unroll
    for (int ct = 0; ct < 8; ++ct) {
      float val = acc[ct][0] + acc[ct][1] + acc[ct][2] + acc[ct][3];
      val += __shfl_xor(val, 16, 64);                // combine 4 lane-groups
      val += __shfl_xor(val, 32, 64);
      if (lane < 16) atomicAdd(&pool_shf[ct * 16 + l15], val);
    }
  } else {
    const int glast = batch[rlast];
    for (int g = g0; g <= glast; ++g) {              // few graphs per boundary chunk
#pragma unroll
      for (int ct = 0; ct < 8; ++ct) {
        float val = 0.f;
#pragma unroll
        for (int r = 0; r < 4; ++r)
          if (glane[r] == g) val += acc[ct][r];
        val += __shfl_xor(val, 16, 64);
        val += __shfl_xor(val, 32, 64);
        if (lane < 16)
          atomicAdd(out + (size_t)g * (N_LAYERS * HID) + lofs + ct * 16 + l15, val);
      }
    }
  }
  __syncthreads();                                   // h in Zbuf + pool_shf ready

  if (store_h) {  // coalesced bf16 h store (16B per thread-chunk)
#pragma unroll
    for (int i = 0; i < 4; ++i) {
      int g = tid + i * 512;
      int r = g >> 4, kc = g & 15;
      if (row0 + r < N_NODES)
        hout[(size_t)(row0 + r) * 16 + kc] =
            *reinterpret_cast<const u16x8*>(&Zbuf[r * LDK + kc * 8]);
    }
  }
  if (uniform && tid < HID)
    atomicAdd(out + (size_t)g0 * (N_LAYERS * HID) + lofs + tid, pool_shf[tid]);
}

extern "C" void kernel_launch(void* const* d_in, const int* in_sizes, int n_in,
                              void* d_out, int out_size, void* d_ws, size_t ws_size,
                              hipStream_t stream) {
  const float* x    = (const float*)d_in[0];
  const int*   ei   = (const int*)d_in[1];          // [2, N_EDGES]
  const int*   batch= (const int*)d_in[2];
  const float* imp  = (const float*)d_in[3];
  const float* W1   = (const float*)d_in[4];        // [3,128,128]
  const float* b1   = (const float*)d_in[5];        // [3,128]
  const float* W2   = (const float*)d_in[6];
  const float* b2   = (const float*)d_in[7];
  float* out = (float*)d_out;                       // [64, 384]

  const int* src = ei;
  const int* dst = ei + N_EDGES;

  // workspace layout (all 16B-aligned)
  char* w = (char*)d_ws;
  unsigned int* hb0 = (unsigned int*)w; w += (size_t)N_NODES * 64 * sizeof(int);  // 12.8MB
  unsigned int* hb1 = (unsigned int*)w; w += (size_t)N_NODES * 64 * sizeof(int);  // 12.8MB
  unsigned short* wt = (unsigned short*)w; w += (size_t)6 * HID * HID * sizeof(short);
  int* esrc   = (int*)w;            w += (size_t)N_EDGES * sizeof(int);           // 2.4MB
  int* deg    = (int*)w;            w += (size_t)DEG_PAD * sizeof(int);
  int* bsum   = (int*)w;            w += 64 * sizeof(int);
  int* cursor = (int*)w;            w += (size_t)N_NODES * sizeof(int);
  int* rowptr = (int*)w;            w += ((size_t)N_NODES + 1) * sizeof(int);

  prep_kernel<<<2048, 256, 0, stream>>>(x, imp, W1, W2, hb0, wt, deg, out);
  hist_kernel<<<(N_EDGES + 255) / 256, 256, 0, stream>>>(dst, deg);
  scan1_kernel<<<SCAN_BLOCKS, 256, 0, stream>>>(deg, bsum);
  scan3_kernel<<<SCAN_BLOCKS, 256, 0, stream>>>(deg, bsum, rowptr, cursor);
  scatter_kernel<<<(N_EDGES + 255) / 256, 256, 0, stream>>>(src, dst, cursor, esrc);

  const int grid = (N_NODES + 127) / 128;           // 391 chunks
  // h ping-pong: l0 hb0->hb1, l1 hb1->hb0, l2 hb0->(skip)
  const unsigned int* hin[3] = {hb0, hb1, hb0};
  unsigned int* hout[3] = {hb1, hb0, hb1};
  for (int l = 0; l < N_LAYERS; ++l) {
    layer_kernel<<<grid, 512, 0, stream>>>(
        hin[l], rowptr, esrc,
        wt + (size_t)l * HID * HID, b1 + (size_t)l * HID,
        wt + (size_t)(3 + l) * HID * HID, b2 + (size_t)l * HID,
        imp, batch, (u16x8*)hout[l], out, l * HID,
        (l < N_LAYERS - 1) ? 1 : 0);
  }
}